// Round 2
// baseline (255.017 us; speedup 1.0000x reference)
//
#include <hip/hip_runtime.h>

// Demosaic (Malvar-He-Cutler), RGGB, B=16 H=W=1024, f32 in/out. v6:
// v4/v5 both formed pointers into a local float v[8][8] window
// (const float* r0 = v[i]) — pointer escape defeats SROA, so the window
// plausibly lived in scratch (256 B/thread -> ~890 MB scratch traffic
// ~= the entire observed 120 us kernel time; explains v5's null result).
// v6 removes the intermediate array entirely: compute reads the load
// registers Lq/Cq/Rq directly through a compile-time-folded selector
// macro VE(r,c). No local arrays, no pointers, nothing escapes ->
// guaranteed register residency. launch_bounds min-waves clamp dropped
// so the allocator is never forced to spill to meet a VGPR cap.
//
// Site map (RGGB): (0,0) R site: R=c, G=kG, B=k4
//                  (0,1) G@R-row: G=c, R=k2, B=k3
//                  (1,0) G@B-row: G=c, R=k3, B=k2
//                  (1,1) B site:  B=c, G=kG, R=k4

constexpr int Bn = 16, Hn = 1024, Wn = 1024;
constexpr int TR = 4;                // output rows per thread

typedef float vfloat4 __attribute__((ext_vector_type(4)));
typedef float vfloat2 __attribute__((ext_vector_type(2)));

// Window element (r in 0..7 rows, c in 0..7 cols), all indices
// compile-time constants after full unroll -> ternaries fold away.
#define VE(r, c) ( (c) == 0 ? Lq[(r)].x : \
                   (c) == 1 ? Lq[(r)].y : \
                   (c) == 2 ? Cq[(r)].x : \
                   (c) == 3 ? Cq[(r)].y : \
                   (c) == 4 ? Cq[(r)].z : \
                   (c) == 5 ? Cq[(r)].w : \
                   (c) == 6 ? Rq[(r)].x : \
                              Rq[(r)].y )

__global__ __launch_bounds__(256) void demosaic_v6(
    const float* __restrict__ src, float* __restrict__ out)
{
    const int t  = threadIdx.x;          // 0..255 -> cols 4t..4t+3 (full width)
    const int y0 = blockIdx.x * TR;      // even
    const int b  = blockIdx.y;

    const float* sb = src + (size_t)b * Hn * Wn;

    const bool tL = (t == 0);
    const bool tR = (t == 255);
    const int xc = 4 * t;
    const int xl = tL ? 0 : xc - 2;          // 8B-aligned; clamped, zeroed below
    const int xr = tR ? (Wn - 2) : (xc + 4); // 8B-aligned; clamped, zeroed below

    // ---- Phase 1: 24 exact-window loads (8 rows x {8B,16B,8B}), independent.
    vfloat2 Lq[8]; vfloat4 Cq[8]; vfloat2 Rq[8];
    #pragma unroll
    for (int r = 0; r < 8; ++r) {
        int gy = y0 - 2 + r;
        int gyc = gy < 0 ? 0 : (gy > Hn - 1 ? Hn - 1 : gy);   // address-safe
        const float* p = sb + (size_t)gyc * Wn;
        Cq[r] = *(const vfloat4*)(p + xc);
        Lq[r] = *(const vfloat2*)(p + xl);
        Rq[r] = *(const vfloat2*)(p + xr);
    }

    // ---- Phase 2a: lane-edge zeroing in place (only t==0 / t==255 lanes).
    #pragma unroll
    for (int r = 0; r < 8; ++r) {
        if (tL) Lq[r] = vfloat2{0.f, 0.f};
        if (tR) Rq[r] = vfloat2{0.f, 0.f};
    }
    // ---- Phase 2b: image top/bottom zeroing — block-uniform scalar branch,
    //      taken by 2 of 256 y-blocks only. In-place, no extra registers.
    if (y0 == 0) {
        #pragma unroll
        for (int r = 0; r < 2; ++r) {
            Lq[r] = vfloat2{0.f, 0.f};
            Cq[r] = vfloat4{0.f, 0.f, 0.f, 0.f};
            Rq[r] = vfloat2{0.f, 0.f};
        }
    }
    if (y0 == Hn - TR) {
        #pragma unroll
        for (int r = 6; r < 8; ++r) {
            Lq[r] = vfloat2{0.f, 0.f};
            Cq[r] = vfloat4{0.f, 0.f, 0.f, 0.f};
            Rq[r] = vfloat2{0.f, 0.f};
        }
    }

    const size_t HW = (size_t)Hn * Wn;
    float* ob = out + (size_t)b * 3 * HW + (size_t)y0 * Wn + xc;

    // ---- Phase 3: compute 4 output rows directly from load registers,
    //      store each as 3x nontemporal float4. No intermediate array.
    #pragma unroll
    for (int i = 0; i < TR; ++i) {
        float R[4], G[4], Bc[4];
        #pragma unroll
        for (int j = 0; j < 4; ++j) {
            const float c   = VE(i + 2, j + 2);
            const float h1  = VE(i + 2, j + 1) + VE(i + 2, j + 3);
            const float v1  = VE(i + 1, j + 2) + VE(i + 3, j + 2);
            const float h2  = VE(i + 2, j + 0) + VE(i + 2, j + 4);
            const float v2s = VE(i + 0, j + 2) + VE(i + 4, j + 2);
            const float ax2 = h2 + v2s;
            const float dg  = VE(i + 1, j + 1) + VE(i + 1, j + 3)
                            + VE(i + 3, j + 1) + VE(i + 3, j + 3);

            const int py = i & 1;            // compile-time (y0 even)
            const int px = j & 1;            // compile-time
            if (px == 0 && py == 0) {        // R site
                R[j] = c;
                G[j] = 0.5f * c + 0.25f * (h1 + v1) - 0.125f * ax2;
                Bc[j] = 0.75f * c + 0.25f * dg - 0.1875f * ax2;
            } else if (px == 1 && py == 0) { // G on R row
                R[j] = 0.625f * c + 0.5f * h1 - 0.125f * h2 + 0.0625f * v2s - 0.125f * dg;
                G[j] = c;
                Bc[j] = 0.625f * c + 0.5f * v1 - 0.125f * v2s + 0.0625f * h2 - 0.125f * dg;
            } else if (px == 0 && py == 1) { // G on B row
                R[j] = 0.625f * c + 0.5f * v1 - 0.125f * v2s + 0.0625f * h2 - 0.125f * dg;
                G[j] = c;
                Bc[j] = 0.625f * c + 0.5f * h1 - 0.125f * h2 + 0.0625f * v2s - 0.125f * dg;
            } else {                         // B site
                R[j] = 0.75f * c + 0.25f * dg - 0.1875f * ax2;
                G[j] = 0.5f * c + 0.25f * (h1 + v1) - 0.125f * ax2;
                Bc[j] = c;
            }
        }

        vfloat4 r4v = {R[0], R[1], R[2], R[3]};
        vfloat4 g4v = {G[0], G[1], G[2], G[3]};
        vfloat4 b4v = {Bc[0], Bc[1], Bc[2], Bc[3]};
        float* o = ob + (size_t)i * Wn;
        __builtin_nontemporal_store(r4v, (vfloat4*)o);
        __builtin_nontemporal_store(g4v, (vfloat4*)(o + HW));
        __builtin_nontemporal_store(b4v, (vfloat4*)(o + 2 * HW));
    }
}

extern "C" void kernel_launch(void* const* d_in, const int* in_sizes, int n_in,
                              void* d_out, int out_size, void* d_ws, size_t ws_size,
                              hipStream_t stream) {
    const float* cfa = (const float*)d_in[0];
    float* out = (float*)d_out;

    dim3 grid(Hn / TR, Bn);              // 256 x 16 = 4096 blocks, 256 thr each
    demosaic_v6<<<grid, dim3(256), 0, stream>>>(cfa, out);
}